// Round 9
// baseline (667.672 us; speedup 1.0000x reference)
//
#include <hip/hip_runtime.h>
#include <math.h>

#define N_ROWS 32768
#define K_CODES 8192
#define DIM 512
#define Q_OFF ((size_t)N_ROWS * DIM)   // 16777216 floats of quantized output

#define NSPLIT 2                        // codebook split across blockIdx.y
#define KSPL (K_CODES / NSPLIT)         // 4096 codes per block
#define NPOOL (NSPLIT * 2)              // 4 disjoint 2048-code pools per row
#define MARGIN_V 0.025f                 // v = d/2 - ||x||^2/2 units; ~23 sigma of f16 err

typedef _Float16 half8 __attribute__((ext_vector_type(8)));
typedef float f32x4 __attribute__((ext_vector_type(4)));

#define GLOAD_LDS(src, dst)                                                        \
  __builtin_amdgcn_global_load_lds(                                                \
      (const __attribute__((address_space(1))) void*)(src),                        \
      (__attribute__((address_space(3))) void*)(dst), 16, 0, 0)

// ---------------------------------------------------------------------------
// f32 -> f16 plane pack (16 floats per thread -> 2 half8)
// ---------------------------------------------------------------------------
__global__ __launch_bounds__(256) void vq_pack_f16(const float4* __restrict__ src,
                                                   half8* __restrict__ dst, int n8) {
    int i = blockIdx.x * 256 + threadIdx.x;
    if (i >= n8) return;
    float4 a = src[i * 2], b = src[i * 2 + 1];
    float v[8] = {a.x, a.y, a.z, a.w, b.x, b.y, b.z, b.w};
    half8 h;
#pragma unroll
    for (int k = 0; k < 8; ++k) h[k] = (_Float16)v[k];
    dst[i] = h;
}

// ---------------------------------------------------------------------------
// zero histogram counts + compute 0.5*||e||^2 per code (one wave/code)
// ---------------------------------------------------------------------------
__global__ __launch_bounds__(256) void vq_esq_init(const float* __restrict__ emb,
                                                   float* __restrict__ esqh,
                                                   int* __restrict__ counts) {
    int gid = blockIdx.x * 256 + threadIdx.x;
    if (gid < K_CODES) counts[gid] = 0;
    int code = gid >> 6;
    int lane = gid & 63;
    const float4* p = reinterpret_cast<const float4*>(emb + (size_t)code * DIM);
    float s = 0.f;
#pragma unroll
    for (int k = 0; k < 2; ++k) {
        float4 v = p[lane + 64 * k];
        s += v.x * v.x + v.y * v.y + v.z * v.z + v.w * v.w;
    }
#pragma unroll
    for (int off = 32; off > 0; off >>= 1) s += __shfl_down(s, off);
    if (lane == 0) esqh[code] = 0.5f * s;
}

// old-swizzle reader, used by fallback kernel only
__device__ __forceinline__ half8 frag16(const _Float16* t, int row, int kg) {
    return *reinterpret_cast<const half8*>(t + row * 32 + ((kg ^ (row & 3)) << 3));
}

// ---------------------------------------------------------------------------
// MFMA argmin, single f16 plane, r4-proven skeleton.
// Block tile 128 rows x 256 codes, 4 waves (wr = wid>>1 row-halves of 64,
// wc = wid&1 code-halves of 128), wave 64x128 via 4x8 frags of
// mfma_f32_16x16x32_f16 (12 ds_reads -> 32 MFMA per wave-step).
// Double-buffered LDS 2 x 24 KB (A 4096 | B 8192 halves), global_load_lds
// staging (6/wave/step), plain {stage-next; compute; __syncthreads} loop --
// the implicit drain is covered because compute/barrier (621 cyc/block, 2
// blocks/CU) exceeds memory latency.  grid (256,2) = 512 blocks = 2/CU.
// All frag addresses = one per-lane base + compile-time immediates; 16B-slot
// XOR swizzle by ((row>>2)&3) on both staging source and read.
// v = 0.5||e||^2 - x.e ; per-lane running top-2 -> shfl_xor tree at end.
// ---------------------------------------------------------------------------
__global__ __launch_bounds__(256, 2) void vq_argmin_f16s(
        const _Float16* __restrict__ xh, const _Float16* __restrict__ eh,
        const float* __restrict__ esqh,
        float* __restrict__ v1o, float* __restrict__ v2o,
        unsigned int* __restrict__ io) {
    __shared__ __align__(16) _Float16 sbuf[2][12288];   // per buf: A 4096 | B 8192 halves

    const int tid = threadIdx.x;
    const int lane = tid & 63;
    const int wid = tid >> 6;             // 0..3
    const int wr = wid >> 1;              // 0..1 : rows wr*64 .. wr*64+63
    const int wc = wid & 1;               // 0..1 : codes wc*128 .. wc*128+127
    const int lr = lane & 15, kg = lane >> 4;
    const int row0 = blockIdx.x * 128;
    const int csplit0 = blockIdx.y * KSPL;
    const int NCC = KSPL / 256;           // 16 cc-tiles of 256 codes
    const int NS = NCC * 16;              // 256 K-steps

    // staging: per-lane inverse-swizzled global offset, wave-uniform LDS dest.
    int offA[2], dstA[2], offB[4], dstB[4];
#pragma unroll
    for (int c = 0; c < 2; ++c) {
        int r = wid * 32 + c * 16 + (lane >> 2);
        int sx = (lane & 3) ^ ((r >> 2) & 3);
        offA[c] = r * DIM + sx * 8;
        dstA[c] = (wid * 32 + c * 16) * 32;
    }
#pragma unroll
    for (int c = 0; c < 4; ++c) {
        int r = wid * 64 + c * 16 + (lane >> 2);
        int sx = (lane & 3) ^ ((r >> 2) & 3);
        offB[c] = r * DIM + sx * 8;
        dstB[c] = 4096 + (wid * 64 + c * 16) * 32;
    }

    auto stage = [&](int b, int s) {   // s = flat K-step (cc*16 + ks)
        int cc = s >> 4, ks = s & 15;
        const _Float16* a0 = xh + (size_t)row0 * DIM + ks * 32;
        const _Float16* b0 = eh + (size_t)(csplit0 + cc * 256) * DIM + ks * 32;
        _Float16* base = &sbuf[b][0];
#pragma unroll
        for (int c = 0; c < 2; ++c) GLOAD_LDS(a0 + offA[c], base + dstA[c]);
#pragma unroll
        for (int c = 0; c < 4; ++c) GLOAD_LDS(b0 + offB[c], base + dstB[c]);
    };

    // single per-lane frag bases; all reads = base + compile-time immediate
    const int swz = (kg ^ ((lr >> 2) & 3)) << 3;
    const int aB = (wr * 64 + lr) * 32 + swz;
    const int bB = 4096 + (wc * 128 + lr) * 32 + swz;

    float rv1[16], rv2[16];
    unsigned int ridx[16];
#pragma unroll
    for (int t = 0; t < 16; ++t) { rv1[t] = INFINITY; rv2[t] = INFINITY; ridx[t] = 0; }

    stage(0, 0);
    __syncthreads();

    int cur = 0;
    for (int cc = 0; cc < NCC; ++cc) {
        f32x4 acc[4][8];
#pragma unroll
        for (int i = 0; i < 4; ++i)
#pragma unroll
            for (int j = 0; j < 8; ++j) acc[i][j] = (f32x4)(0.f);

#pragma unroll
        for (int ks = 0; ks < 16; ++ks) {
            int s = cc * 16 + ks;
            if (s < NS - 1) stage(cur ^ 1, s + 1);

            const _Float16* base = &sbuf[cur][0];
            half8 a[4], b[8];
#pragma unroll
            for (int i = 0; i < 4; ++i)
                a[i] = *reinterpret_cast<const half8*>(base + aB + i * 512);
#pragma unroll
            for (int j = 0; j < 8; ++j)
                b[j] = *reinterpret_cast<const half8*>(base + bB + j * 512);
#pragma unroll
            for (int j = 0; j < 8; ++j)
#pragma unroll
                for (int i = 0; i < 4; ++i)
                    acc[i][j] = __builtin_amdgcn_mfma_f32_16x16x32_f16(a[i], b[j], acc[i][j], 0, 0, 0);

            __syncthreads();
            cur ^= 1;
        }

        // fold tile into per-lane running top-2
#pragma unroll
        for (int j = 0; j < 8; ++j) {
            int cg = csplit0 + cc * 256 + wc * 128 + j * 16 + lr;
            float eqv = esqh[cg];
#pragma unroll
            for (int i = 0; i < 4; ++i) {
#pragma unroll
                for (int r = 0; r < 4; ++r) {
                    float v = eqv - acc[i][j][r];
                    int t = i * 4 + r;
                    if (v < rv1[t]) {
                        rv2[t] = rv1[t]; ridx[t] = (ridx[t] << 16) | (unsigned int)cg; rv1[t] = v;
                    } else if (v < rv2[t]) {
                        rv2[t] = v; ridx[t] = (ridx[t] & 0xFFFFu) | ((unsigned int)cg << 16);
                    }
                }
            }
        }
    }

    // cross-lane top-2 merge within each 16-lane group (same rows, disjoint cols)
#pragma unroll
    for (int m = 1; m <= 8; m <<= 1) {
#pragma unroll
        for (int t = 0; t < 16; ++t) {
            float bv1 = __shfl_xor(rv1[t], m);
            float bv2 = __shfl_xor(rv2[t], m);
            unsigned int ox = (unsigned int)__shfl_xor((int)ridx[t], m);
            unsigned int ai1 = ridx[t] & 0xFFFFu, ai2 = ridx[t] >> 16;
            unsigned int bi1 = ox & 0xFFFFu, bi2 = ox >> 16;
            float av1 = rv1[t], av2 = rv2[t];
            bool bf = (bv1 < av1) || (bv1 == av1 && bi1 < ai1);
            float n1v = bf ? bv1 : av1; unsigned int n1i = bf ? bi1 : ai1;
            float w1v = bf ? av1 : bv1; unsigned int w1i = bf ? ai1 : bi1;
            bool cf = (bv2 < av2) || (bv2 == av2 && bi2 < ai2);
            float c2v = cf ? bv2 : av2; unsigned int c2i = cf ? bi2 : ai2;
            bool df = (c2v < w1v) || (c2v == w1v && c2i < w1i);
            float n2v = df ? c2v : w1v; unsigned int n2i = df ? c2i : w1i;
            rv1[t] = n1v; rv2[t] = n2v; ridx[t] = n1i | (n2i << 16);
        }
    }

    if (lr == 0) {
#pragma unroll
        for (int t = 0; t < 16; ++t) {
            int rl = wr * 64 + (t >> 2) * 16 + kg * 4 + (t & 3);
            size_t o = (size_t)(blockIdx.y * 2 + wc) * N_ROWS + row0 + rl;
            v1o[o] = rv1[t]; v2o[o] = rv2[t]; io[o] = ridx[t];
        }
    }
}

// ---------------------------------------------------------------------------
// Fallback (workspace too small): reg-staged f32->f16, double-buffer,
// __syncthreads, 128x256 tile, 4 waves.  Correctness path only.
// ---------------------------------------------------------------------------
__global__ __launch_bounds__(256, 2) void vq_argmin_fb(
        const float* __restrict__ xf, const float* __restrict__ ef,
        const float* __restrict__ esqh,
        float* __restrict__ v1o, float* __restrict__ v2o,
        unsigned int* __restrict__ io) {
    __shared__ __align__(16) _Float16 sbuf[2][12288];

    const int tid = threadIdx.x;
    const int lane = tid & 63;
    const int wid = tid >> 6;
    const int wr = wid >> 1, wc = wid & 1;
    const int lr = lane & 15, kg = lane >> 4;
    const int row0 = blockIdx.x * 128;
    const int csplit0 = blockIdx.y * KSPL;

    auto stage = [&](int b, int s) {
        int cc = s >> 4, ks = s & 15;
        {
            const int r = tid >> 1;
            const int k0 = (tid & 1) * 16;
            const float4* xp = reinterpret_cast<const float4*>(
                xf + (size_t)(row0 + r) * DIM + ks * 32 + k0);
            float4 f0 = xp[0], f1 = xp[1], f2 = xp[2], f3 = xp[3];
            float v[16] = {f0.x, f0.y, f0.z, f0.w, f1.x, f1.y, f1.z, f1.w,
                           f2.x, f2.y, f2.z, f2.w, f3.x, f3.y, f3.z, f3.w};
            half8 h0, h1;
#pragma unroll
            for (int k = 0; k < 8; ++k) { h0[k] = (_Float16)v[k]; h1[k] = (_Float16)v[8 + k]; }
            int s0 = (k0 >> 3) ^ (r & 3);
            int s1 = ((k0 >> 3) + 1) ^ (r & 3);
            _Float16* Ah = &sbuf[b][0];
            *reinterpret_cast<half8*>(Ah + r * 32 + s0 * 8) = h0;
            *reinterpret_cast<half8*>(Ah + r * 32 + s1 * 8) = h1;
        }
        {
            const int r = tid;
            const float4* ep = reinterpret_cast<const float4*>(
                ef + (size_t)(csplit0 + cc * 256 + r) * DIM + ks * 32);
            _Float16* Be = &sbuf[b][4096];
#pragma unroll
            for (int q = 0; q < 4; ++q) {
                float4 g0 = ep[q * 2], g1 = ep[q * 2 + 1];
                half8 h;
                h[0] = (_Float16)g0.x; h[1] = (_Float16)g0.y;
                h[2] = (_Float16)g0.z; h[3] = (_Float16)g0.w;
                h[4] = (_Float16)g1.x; h[5] = (_Float16)g1.y;
                h[6] = (_Float16)g1.z; h[7] = (_Float16)g1.w;
                *reinterpret_cast<half8*>(Be + r * 32 + ((q ^ (r & 3)) << 3)) = h;
            }
        }
    };

    float rv1[16], rv2[16];
    unsigned int ridx[16];
#pragma unroll
    for (int t = 0; t < 16; ++t) { rv1[t] = INFINITY; rv2[t] = INFINITY; ridx[t] = 0; }

    f32x4 acc[4][8];
    const int NS = (KSPL / 256) * 16;
    int cur = 0;
    stage(0, 0);
    __syncthreads();
    for (int s = 0; s < NS; ++s) {
        if ((s & 15) == 0) {
#pragma unroll
            for (int i = 0; i < 4; ++i)
#pragma unroll
                for (int j = 0; j < 8; ++j) acc[i][j] = (f32x4)(0.f);
        }
        const _Float16* Ah = &sbuf[cur][0];
        const _Float16* Be = &sbuf[cur][4096];
        half8 a[4];
#pragma unroll
        for (int i = 0; i < 4; ++i) a[i] = frag16(Ah, wr * 64 + i * 16 + lr, kg);
#pragma unroll
        for (int j = 0; j < 8; ++j) {
            half8 b = frag16(Be, wc * 128 + j * 16 + lr, kg);
#pragma unroll
            for (int i = 0; i < 4; ++i)
                acc[i][j] = __builtin_amdgcn_mfma_f32_16x16x32_f16(a[i], b, acc[i][j], 0, 0, 0);
        }
        if (s + 1 < NS) stage(cur ^ 1, s + 1);
        if ((s & 15) == 15) {
            int cc = s >> 4;
#pragma unroll
            for (int j = 0; j < 8; ++j) {
                int cg = csplit0 + cc * 256 + wc * 128 + j * 16 + lr;
                float eqv = esqh[cg];
#pragma unroll
                for (int i = 0; i < 4; ++i) {
#pragma unroll
                    for (int r = 0; r < 4; ++r) {
                        float v = eqv - acc[i][j][r];
                        int t = i * 4 + r;
                        if (v < rv1[t]) {
                            rv2[t] = rv1[t]; ridx[t] = (ridx[t] << 16) | (unsigned int)cg; rv1[t] = v;
                        } else if (v < rv2[t]) {
                            rv2[t] = v; ridx[t] = (ridx[t] & 0xFFFFu) | ((unsigned int)cg << 16);
                        }
                    }
                }
            }
        }
        __syncthreads();
        cur ^= 1;
    }

#pragma unroll
    for (int m = 1; m <= 8; m <<= 1) {
#pragma unroll
        for (int t = 0; t < 16; ++t) {
            float bv1 = __shfl_xor(rv1[t], m);
            float bv2 = __shfl_xor(rv2[t], m);
            unsigned int ox = (unsigned int)__shfl_xor((int)ridx[t], m);
            unsigned int ai1 = ridx[t] & 0xFFFFu, ai2 = ridx[t] >> 16;
            unsigned int bi1 = ox & 0xFFFFu, bi2 = ox >> 16;
            float av1 = rv1[t], av2 = rv2[t];
            bool bf = (bv1 < av1) || (bv1 == av1 && bi1 < ai1);
            float n1v = bf ? bv1 : av1; unsigned int n1i = bf ? bi1 : ai1;
            float w1v = bf ? av1 : bv1; unsigned int w1i = bf ? ai1 : bi1;
            bool cf = (bv2 < av2) || (bv2 == av2 && bi2 < ai2);
            float c2v = cf ? bv2 : av2; unsigned int c2i = cf ? bi2 : ai2;
            bool df = (c2v < w1v) || (c2v == w1v && c2i < w1i);
            float n2v = df ? c2v : w1v; unsigned int n2i = df ? c2i : w1i;
            rv1[t] = n1v; rv2[t] = n2v; ridx[t] = n1i | (n2i << 16);
        }
    }
    if (lr == 0) {
#pragma unroll
        for (int t = 0; t < 16; ++t) {
            int rl = wr * 64 + (t >> 2) * 16 + kg * 4 + (t & 3);
            size_t o = (size_t)(blockIdx.y * 2 + wc) * N_ROWS + row0 + rl;
            v1o[o] = rv1[t]; v2o[o] = rv2[t]; io[o] = ridx[t];
        }
    }
}

// ---------------------------------------------------------------------------
// Per-row (one wave): merge 4 pool top-2s; if global gap < MARGIN_V, fp64
// re-score all 8 candidates; gather embedding row, loss partial, histogram.
// ---------------------------------------------------------------------------
__global__ __launch_bounds__(64) void vq_gather(const float* __restrict__ x,
                                                const float* __restrict__ emb,
                                                const float* __restrict__ v1,
                                                const float* __restrict__ v2,
                                                const unsigned int* __restrict__ io,
                                                float* __restrict__ out,
                                                int* __restrict__ counts,
                                                float* __restrict__ lossp) {
    const int row = blockIdx.x;
    const int lane = threadIdx.x;

    float V1 = INFINITY, V2 = INFINITY;
    unsigned int I1 = 0xFFFFu, I2 = 0xFFFFu;
#pragma unroll
    for (int p = 0; p < NPOOL; ++p) {
        size_t o = (size_t)p * N_ROWS + row;
        float bv1 = v1[o], bv2 = v2[o];
        unsigned int ox = io[o];
        unsigned int bi1 = ox & 0xFFFFu, bi2 = ox >> 16;
        bool bf = (bv1 < V1) || (bv1 == V1 && bi1 < I1);
        float n1v = bf ? bv1 : V1; unsigned int n1i = bf ? bi1 : I1;
        float w1v = bf ? V1 : bv1; unsigned int w1i = bf ? I1 : bi1;
        bool cf = (bv2 < V2) || (bv2 == V2 && bi2 < I2);
        float c2v = cf ? bv2 : V2; unsigned int c2i = cf ? bi2 : I2;
        bool df = (c2v < w1v) || (c2v == w1v && c2i < w1i);
        V1 = n1v; I1 = n1i;
        V2 = df ? c2v : w1v; I2 = df ? c2i : w1i;
    }

    int c = (int)I1;
    if (V2 - V1 < MARGIN_V) {
        unsigned int cand[8];
#pragma unroll
        for (int p = 0; p < NPOOL; ++p) {
            unsigned int ox = io[(size_t)p * N_ROWS + row];
            cand[2 * p] = ox & 0xFFFFu;
            cand[2 * p + 1] = ox >> 16;
        }
        double xd[8];
#pragma unroll
        for (int kk = 0; kk < 8; ++kk)
            xd[kk] = (double)x[(size_t)row * DIM + lane + 64 * kk];
        double best = 1e300;
        unsigned int bi = 0xFFFFFFFFu;
#pragma unroll
        for (int t = 0; t < 8; ++t) {
            const float* e1 = emb + (size_t)cand[t] * DIM;
            double d = 0.0;
#pragma unroll
            for (int kk = 0; kk < 8; ++kk) {
                double df = xd[kk] - (double)e1[lane + 64 * kk];
                d = fma(df, df, d);
            }
#pragma unroll
            for (int m = 1; m <= 32; m <<= 1) d += __shfl_xor(d, m);
            if (d < best || (d == best && cand[t] < bi)) { best = d; bi = cand[t]; }
        }
        c = (int)bi;
    }

    const float4* xr4 = reinterpret_cast<const float4*>(x + (size_t)row * DIM);
    const float4* er4 = reinterpret_cast<const float4*>(emb + (size_t)c * DIM);
    float4* qo = reinterpret_cast<float4*>(out + (size_t)row * DIM);
    float lsum = 0.f;
#pragma unroll
    for (int k = 0; k < 2; ++k) {
        int idx = lane + 64 * k;
        float4 e = er4[idx];
        float4 xv = xr4[idx];
        qo[idx] = e;
        float dx = xv.x - e.x, dy = xv.y - e.y, dz = xv.z - e.z, dw = xv.w - e.w;
        lsum += dx * dx + dy * dy + dz * dz + dw * dw;
    }
#pragma unroll
    for (int off = 32; off > 0; off >>= 1) lsum += __shfl_down(lsum, off);
    if (lane == 0) {
        lossp[row] = lsum;
        atomicAdd(&counts[c], 1);
        out[Q_OFF + 2 + row] = (float)c;   // indices as float (d_out is f32)
    }
}

// ---------------------------------------------------------------------------
// Single block: fp64 loss sum + perplexity, write scalars.
// ---------------------------------------------------------------------------
__global__ __launch_bounds__(256) void vq_finalize(const float* __restrict__ lossp,
                                                   const int* __restrict__ counts,
                                                   float* __restrict__ out) {
    __shared__ double sred[8];
    const int tid = threadIdx.x;
    const int lane = tid & 63, wv = tid >> 6;
    double ls = 0.0, hs = 0.0;
    for (int r = tid; r < N_ROWS; r += 256) ls += (double)lossp[r];
    for (int cidx = tid; cidx < K_CODES; cidx += 256) {
        double p = (double)counts[cidx] * (1.0 / (double)N_ROWS);
        hs += p * log(p + 1e-10);
    }
#pragma unroll
    for (int off = 32; off > 0; off >>= 1) {
        ls += __shfl_down(ls, off);
        hs += __shfl_down(hs, off);
    }
    if (lane == 0) { sred[wv] = ls; sred[4 + wv] = hs; }
    __syncthreads();
    if (tid == 0) {
        double L = sred[0] + sred[1] + sred[2] + sred[3];
        double H = sred[4] + sred[5] + sred[6] + sred[7];
        out[Q_OFF]     = (float)(0.25 * L / (double)Q_OFF);   // commitment loss
        out[Q_OFF + 1] = (float)exp(-H);                      // perplexity
    }
}

// ---------------------------------------------------------------------------
extern "C" void kernel_launch(void* const* d_in, const int* in_sizes, int n_in,
                              void* d_out, int out_size, void* d_ws, size_t ws_size,
                              hipStream_t stream) {
    const float* x   = (const float*)d_in[0];
    const float* emb = (const float*)d_in[1];
    float* out = (float*)d_out;

    // workspace layout (u32 words)
    unsigned int* w = (unsigned int*)d_ws;
    float* esqh         = (float*)(w);                       // 8192
    int*   counts       = (int*)(w + 8192);                  // 8192
    float* lossp        = (float*)(w + 16384);               // 32768
    float* v1           = (float*)(w + 49152);               // 4*32768
    float* v2           = (float*)(w + 180224);              // 4*32768
    unsigned int* io    = (unsigned int*)(w + 311296);       // 4*32768
    _Float16* x_h       = (_Float16*)(w + 442368);           // 16.7M halves (32 MB)
    _Float16* e_h       = (_Float16*)(w + 8830976);          // 4.2M halves (8 MB)
    const size_t need   = (size_t)10928128 * 4;              // ~43.7 MB

    const bool pk = ws_size >= need;

    vq_esq_init<<<(K_CODES * 64) / 256, 256, 0, stream>>>(emb, esqh, counts);
    if (pk) {
        vq_pack_f16<<<(N_ROWS * DIM / 8) / 256, 256, 0, stream>>>(
            (const float4*)x, (half8*)x_h, N_ROWS * DIM / 8);
        vq_pack_f16<<<(K_CODES * DIM / 8) / 256, 256, 0, stream>>>(
            (const float4*)emb, (half8*)e_h, K_CODES * DIM / 8);
    }

    dim3 grid(N_ROWS / 128, NSPLIT);
    if (pk)
        vq_argmin_f16s<<<grid, 256, 0, stream>>>(x_h, e_h, esqh, v1, v2, io);
    else
        vq_argmin_fb<<<grid, 256, 0, stream>>>(x, emb, esqh, v1, v2, io);

    vq_gather<<<N_ROWS, 64, 0, stream>>>(x, emb, v1, v2, io, out, counts, lossp);
    vq_finalize<<<1, 256, 0, stream>>>(lossp, counts, out);
}

// Round 10
// 608.053 us; speedup vs baseline: 1.0980x; 1.0980x over previous
//
#include <hip/hip_runtime.h>
#include <math.h>

#define N_ROWS 32768
#define K_CODES 8192
#define DIM 512
#define Q_OFF ((size_t)N_ROWS * DIM)   // 16777216 floats of quantized output

#define NSPLIT 2                        // codebook split (one half per XCD group)
#define KSPL (K_CODES / NSPLIT)         // 4096 codes per block
#define NPOOL (NSPLIT * 2)              // 4 disjoint 2048-code pools per row
#define MARGIN_V 0.025f                 // v = d/2 - ||x||^2/2 units; ~23 sigma of f16 err

typedef _Float16 half8 __attribute__((ext_vector_type(8)));
typedef float f32x4 __attribute__((ext_vector_type(4)));

#define GLOAD_LDS(src, dst)                                                        \
  __builtin_amdgcn_global_load_lds(                                                \
      (const __attribute__((address_space(1))) void*)(src),                        \
      (__attribute__((address_space(3))) void*)(dst), 16, 0, 0)

// ---------------------------------------------------------------------------
// f32 -> f16 plane pack (16 floats per thread -> 2 half8)
// ---------------------------------------------------------------------------
__global__ __launch_bounds__(256) void vq_pack_f16(const float4* __restrict__ src,
                                                   half8* __restrict__ dst, int n8) {
    int i = blockIdx.x * 256 + threadIdx.x;
    if (i >= n8) return;
    float4 a = src[i * 2], b = src[i * 2 + 1];
    float v[8] = {a.x, a.y, a.z, a.w, b.x, b.y, b.z, b.w};
    half8 h;
#pragma unroll
    for (int k = 0; k < 8; ++k) h[k] = (_Float16)v[k];
    dst[i] = h;
}

// ---------------------------------------------------------------------------
// zero histogram counts + compute 0.5*||e||^2 per code (one wave/code)
// ---------------------------------------------------------------------------
__global__ __launch_bounds__(256) void vq_esq_init(const float* __restrict__ emb,
                                                   float* __restrict__ esqh,
                                                   int* __restrict__ counts) {
    int gid = blockIdx.x * 256 + threadIdx.x;
    if (gid < K_CODES) counts[gid] = 0;
    int code = gid >> 6;
    int lane = gid & 63;
    const float4* p = reinterpret_cast<const float4*>(emb + (size_t)code * DIM);
    float s = 0.f;
#pragma unroll
    for (int k = 0; k < 2; ++k) {
        float4 v = p[lane + 64 * k];
        s += v.x * v.x + v.y * v.y + v.z * v.z + v.w * v.w;
    }
#pragma unroll
    for (int off = 32; off > 0; off >>= 1) s += __shfl_down(s, off);
    if (lane == 0) esqh[code] = 0.5f * s;
}

// old-swizzle reader, used by fallback kernel only
__device__ __forceinline__ half8 frag16(const _Float16* t, int row, int kg) {
    return *reinterpret_cast<const half8*>(t + row * 32 + ((kg ^ (row & 3)) << 3));
}

// ---------------------------------------------------------------------------
// MFMA argmin, single f16 plane, triple-buffered counted-vmcnt pipeline.
// Block tile 128 rows x 256 codes, 4 waves (wr 2 x wc 2), wave 64x128 via
// 4x8 frags of mfma_f32_16x16x32_f16 (12 ds_reads -> 32 MFMA per K-step).
// LDS: 3 buffers x 24 KB (A 4096 | B 8192 halves) = 72 KB, 2 blocks/CU.
// Pipeline (r6-proven): depth-2 global_load_lds prefetch, per-step
// {s_waitcnt vmcnt(6); s_barrier; stage(s+2); compute(cur)}; vmcnt(0) only
// at the final step of the peeled last cc-tile.  Buffer rotation = one
// uniform base add per step (cur is runtime, loop fully unrolled).
// XCD mapping: xcd = bid&7 owns ONE codebook half (L2-resident 4 MB) and a
// contiguous x range: y = xcd>>2, x = (bid>>3) + 64*(xcd&3)  (bijective).
// v = 0.5||e||^2 - x.e ; per-lane running top-2 -> shfl_xor tree at end.
// ---------------------------------------------------------------------------
__global__ __launch_bounds__(256, 2) void vq_argmin_f16t(
        const _Float16* __restrict__ xh, const _Float16* __restrict__ eh,
        const float* __restrict__ esqh,
        float* __restrict__ v1o, float* __restrict__ v2o,
        unsigned int* __restrict__ io) {
    __shared__ __align__(16) _Float16 sbuf[3][12288];   // per buf: A 4096 | B 8192 halves

    const int tid = threadIdx.x;
    const int lane = tid & 63;
    const int wid = tid >> 6;             // 0..3
    const int wr = wid >> 1;              // 0..1 : rows wr*64 .. wr*64+63
    const int wc = wid & 1;               // 0..1 : codes wc*128 .. wc*128+127
    const int lr = lane & 15, kg = lane >> 4;

    const int bid = blockIdx.x;           // 0..511
    const int xcd = bid & 7;
    const int by  = xcd >> 2;             // codebook half for this XCD
    const int bx  = (bid >> 3) + ((xcd & 3) << 6);
    const int row0 = bx * 128;
    const int csplit0 = by * KSPL;
    const int NCC = KSPL / 256;           // 16 cc-tiles of 256 codes
    const int NS = NCC * 16;              // 256 K-steps

    // staging: per-lane inverse-swizzled global offset, wave-uniform LDS dest.
    int offA[2], dstA[2], offB[4], dstB[4];
#pragma unroll
    for (int c = 0; c < 2; ++c) {
        int r = wid * 32 + c * 16 + (lane >> 2);
        int sx = (lane & 3) ^ ((r >> 2) & 3);
        offA[c] = r * DIM + sx * 8;
        dstA[c] = (wid * 32 + c * 16) * 32;
    }
#pragma unroll
    for (int c = 0; c < 4; ++c) {
        int r = wid * 64 + c * 16 + (lane >> 2);
        int sx = (lane & 3) ^ ((r >> 2) & 3);
        offB[c] = r * DIM + sx * 8;
        dstB[c] = 4096 + (wid * 64 + c * 16) * 32;
    }

    _Float16* sb = &sbuf[0][0];

    auto stage = [&](_Float16* base, int s) {   // s = flat K-step (cc*16 + ks)
        int cc = s >> 4, ks = s & 15;
        const _Float16* a0 = xh + (size_t)row0 * DIM + ks * 32;
        const _Float16* b0 = eh + (size_t)(csplit0 + cc * 256) * DIM + ks * 32;
#pragma unroll
        for (int c = 0; c < 2; ++c) GLOAD_LDS(a0 + offA[c], base + dstA[c]);
#pragma unroll
        for (int c = 0; c < 4; ++c) GLOAD_LDS(b0 + offB[c], base + dstB[c]);
    };

    // single per-lane frag bases; all reads = rotating base + compile-time imm
    const int swz = (kg ^ ((lr >> 2) & 3)) << 3;
    const int aB = (wr * 64 + lr) * 32 + swz;
    const int bB = 4096 + (wc * 128 + lr) * 32 + swz;

    auto compute = [&](const _Float16* base, f32x4 (&acc)[4][8]) {
        half8 a[4], b[8];
#pragma unroll
        for (int i = 0; i < 4; ++i)
            a[i] = *reinterpret_cast<const half8*>(base + aB + i * 512);
#pragma unroll
        for (int j = 0; j < 8; ++j)
            b[j] = *reinterpret_cast<const half8*>(base + bB + j * 512);
#pragma unroll
        for (int j = 0; j < 8; ++j)
#pragma unroll
            for (int i = 0; i < 4; ++i)
                acc[i][j] = __builtin_amdgcn_mfma_f32_16x16x32_f16(a[i], b[j], acc[i][j], 0, 0, 0);
    };

    float rv1[16], rv2[16];
    unsigned int ridx[16];
#pragma unroll
    for (int t = 0; t < 16; ++t) { rv1[t] = INFINITY; rv2[t] = INFINITY; ridx[t] = 0; }

    auto fold = [&](int cc, f32x4 (&acc)[4][8]) {
#pragma unroll
        for (int j = 0; j < 8; ++j) {
            int cg = csplit0 + cc * 256 + wc * 128 + j * 16 + lr;
            float eqv = esqh[cg];
#pragma unroll
            for (int i = 0; i < 4; ++i) {
#pragma unroll
                for (int r = 0; r < 4; ++r) {
                    float v = eqv - acc[i][j][r];
                    int t = i * 4 + r;
                    if (v < rv1[t]) {
                        rv2[t] = rv1[t]; ridx[t] = (ridx[t] << 16) | (unsigned int)cg; rv1[t] = v;
                    } else if (v < rv2[t]) {
                        rv2[t] = v; ridx[t] = (ridx[t] & 0xFFFFu) | ((unsigned int)cg << 16);
                    }
                }
            }
        }
    };

    stage(sb, 0);
    stage(sb + 12288, 1);

    int cur = 0;
    for (int cc = 0; cc < NCC - 1; ++cc) {
        f32x4 acc[4][8];
#pragma unroll
        for (int i = 0; i < 4; ++i)
#pragma unroll
            for (int j = 0; j < 8; ++j) acc[i][j] = (f32x4)(0.f);
#pragma unroll
        for (int ks = 0; ks < 16; ++ks) {
            asm volatile("s_waitcnt vmcnt(6)" ::: "memory");
            __builtin_amdgcn_s_barrier();
            int n2 = cur + 2; if (n2 >= 3) n2 -= 3;
            stage(sb + n2 * 12288, cc * 16 + ks + 2);
            compute(sb + cur * 12288, acc);
            cur += 1; if (cur == 3) cur = 0;
        }
        fold(cc, acc);
    }
    {   // peeled last cc-tile: stage while ks<14, drain only at ks==15
        const int cc = NCC - 1;
        f32x4 acc[4][8];
#pragma unroll
        for (int i = 0; i < 4; ++i)
#pragma unroll
            for (int j = 0; j < 8; ++j) acc[i][j] = (f32x4)(0.f);
#pragma unroll
        for (int ks = 0; ks < 16; ++ks) {
            if (ks == 15) asm volatile("s_waitcnt vmcnt(0)" ::: "memory");
            else          asm volatile("s_waitcnt vmcnt(6)" ::: "memory");
            __builtin_amdgcn_s_barrier();
            if (ks < 14) {
                int n2 = cur + 2; if (n2 >= 3) n2 -= 3;
                stage(sb + n2 * 12288, cc * 16 + ks + 2);
            }
            compute(sb + cur * 12288, acc);
            cur += 1; if (cur == 3) cur = 0;
        }
        fold(cc, acc);
    }

    // cross-lane top-2 merge within each 16-lane group (same rows, disjoint cols)
#pragma unroll
    for (int m = 1; m <= 8; m <<= 1) {
#pragma unroll
        for (int t = 0; t < 16; ++t) {
            float bv1 = __shfl_xor(rv1[t], m);
            float bv2 = __shfl_xor(rv2[t], m);
            unsigned int ox = (unsigned int)__shfl_xor((int)ridx[t], m);
            unsigned int ai1 = ridx[t] & 0xFFFFu, ai2 = ridx[t] >> 16;
            unsigned int bi1 = ox & 0xFFFFu, bi2 = ox >> 16;
            float av1 = rv1[t], av2 = rv2[t];
            bool bf = (bv1 < av1) || (bv1 == av1 && bi1 < ai1);
            float n1v = bf ? bv1 : av1; unsigned int n1i = bf ? bi1 : ai1;
            float w1v = bf ? av1 : bv1; unsigned int w1i = bf ? ai1 : bi1;
            bool cf = (bv2 < av2) || (bv2 == av2 && bi2 < ai2);
            float c2v = cf ? bv2 : av2; unsigned int c2i = cf ? bi2 : ai2;
            bool df = (c2v < w1v) || (c2v == w1v && c2i < w1i);
            float n2v = df ? c2v : w1v; unsigned int n2i = df ? c2i : w1i;
            rv1[t] = n1v; rv2[t] = n2v; ridx[t] = n1i | (n2i << 16);
        }
    }

    if (lr == 0) {
#pragma unroll
        for (int t = 0; t < 16; ++t) {
            int rl = wr * 64 + (t >> 2) * 16 + kg * 4 + (t & 3);
            size_t o = (size_t)(by * 2 + wc) * N_ROWS + row0 + rl;
            v1o[o] = rv1[t]; v2o[o] = rv2[t]; io[o] = ridx[t];
        }
    }
}

// ---------------------------------------------------------------------------
// Fallback (workspace too small): reg-staged f32->f16, double-buffer,
// __syncthreads, 128x256 tile, 4 waves.  Correctness path only.
// ---------------------------------------------------------------------------
__global__ __launch_bounds__(256, 2) void vq_argmin_fb(
        const float* __restrict__ xf, const float* __restrict__ ef,
        const float* __restrict__ esqh,
        float* __restrict__ v1o, float* __restrict__ v2o,
        unsigned int* __restrict__ io) {
    __shared__ __align__(16) _Float16 sbuf[2][12288];

    const int tid = threadIdx.x;
    const int lane = tid & 63;
    const int wid = tid >> 6;
    const int wr = wid >> 1, wc = wid & 1;
    const int lr = lane & 15, kg = lane >> 4;
    const int row0 = blockIdx.x * 128;
    const int csplit0 = blockIdx.y * KSPL;

    auto stage = [&](int b, int s) {
        int cc = s >> 4, ks = s & 15;
        {
            const int r = tid >> 1;
            const int k0 = (tid & 1) * 16;
            const float4* xp = reinterpret_cast<const float4*>(
                xf + (size_t)(row0 + r) * DIM + ks * 32 + k0);
            float4 f0 = xp[0], f1 = xp[1], f2 = xp[2], f3 = xp[3];
            float v[16] = {f0.x, f0.y, f0.z, f0.w, f1.x, f1.y, f1.z, f1.w,
                           f2.x, f2.y, f2.z, f2.w, f3.x, f3.y, f3.z, f3.w};
            half8 h0, h1;
#pragma unroll
            for (int k = 0; k < 8; ++k) { h0[k] = (_Float16)v[k]; h1[k] = (_Float16)v[8 + k]; }
            int s0 = (k0 >> 3) ^ (r & 3);
            int s1 = ((k0 >> 3) + 1) ^ (r & 3);
            _Float16* Ah = &sbuf[b][0];
            *reinterpret_cast<half8*>(Ah + r * 32 + s0 * 8) = h0;
            *reinterpret_cast<half8*>(Ah + r * 32 + s1 * 8) = h1;
        }
        {
            const int r = tid;
            const float4* ep = reinterpret_cast<const float4*>(
                ef + (size_t)(csplit0 + cc * 256 + r) * DIM + ks * 32);
            _Float16* Be = &sbuf[b][4096];
#pragma unroll
            for (int q = 0; q < 4; ++q) {
                float4 g0 = ep[q * 2], g1 = ep[q * 2 + 1];
                half8 h;
                h[0] = (_Float16)g0.x; h[1] = (_Float16)g0.y;
                h[2] = (_Float16)g0.z; h[3] = (_Float16)g0.w;
                h[4] = (_Float16)g1.x; h[5] = (_Float16)g1.y;
                h[6] = (_Float16)g1.z; h[7] = (_Float16)g1.w;
                *reinterpret_cast<half8*>(Be + r * 32 + ((q ^ (r & 3)) << 3)) = h;
            }
        }
    };

    float rv1[16], rv2[16];
    unsigned int ridx[16];
#pragma unroll
    for (int t = 0; t < 16; ++t) { rv1[t] = INFINITY; rv2[t] = INFINITY; ridx[t] = 0; }

    f32x4 acc[4][8];
    const int NS = (KSPL / 256) * 16;
    int cur = 0;
    stage(0, 0);
    __syncthreads();
    for (int s = 0; s < NS; ++s) {
        if ((s & 15) == 0) {
#pragma unroll
            for (int i = 0; i < 4; ++i)
#pragma unroll
                for (int j = 0; j < 8; ++j) acc[i][j] = (f32x4)(0.f);
        }
        const _Float16* Ah = &sbuf[cur][0];
        const _Float16* Be = &sbuf[cur][4096];
        half8 a[4];
#pragma unroll
        for (int i = 0; i < 4; ++i) a[i] = frag16(Ah, wr * 64 + i * 16 + lr, kg);
#pragma unroll
        for (int j = 0; j < 8; ++j) {
            half8 b = frag16(Be, wc * 128 + j * 16 + lr, kg);
#pragma unroll
            for (int i = 0; i < 4; ++i)
                acc[i][j] = __builtin_amdgcn_mfma_f32_16x16x32_f16(a[i], b, acc[i][j], 0, 0, 0);
        }
        if (s + 1 < NS) stage(cur ^ 1, s + 1);
        if ((s & 15) == 15) {
            int cc = s >> 4;
#pragma unroll
            for (int j = 0; j < 8; ++j) {
                int cg = csplit0 + cc * 256 + wc * 128 + j * 16 + lr;
                float eqv = esqh[cg];
#pragma unroll
                for (int i = 0; i < 4; ++i) {
#pragma unroll
                    for (int r = 0; r < 4; ++r) {
                        float v = eqv - acc[i][j][r];
                        int t = i * 4 + r;
                        if (v < rv1[t]) {
                            rv2[t] = rv1[t]; ridx[t] = (ridx[t] << 16) | (unsigned int)cg; rv1[t] = v;
                        } else if (v < rv2[t]) {
                            rv2[t] = v; ridx[t] = (ridx[t] & 0xFFFFu) | ((unsigned int)cg << 16);
                        }
                    }
                }
            }
        }
        __syncthreads();
        cur ^= 1;
    }

#pragma unroll
    for (int m = 1; m <= 8; m <<= 1) {
#pragma unroll
        for (int t = 0; t < 16; ++t) {
            float bv1 = __shfl_xor(rv1[t], m);
            float bv2 = __shfl_xor(rv2[t], m);
            unsigned int ox = (unsigned int)__shfl_xor((int)ridx[t], m);
            unsigned int ai1 = ridx[t] & 0xFFFFu, ai2 = ridx[t] >> 16;
            unsigned int bi1 = ox & 0xFFFFu, bi2 = ox >> 16;
            float av1 = rv1[t], av2 = rv2[t];
            bool bf = (bv1 < av1) || (bv1 == av1 && bi1 < ai1);
            float n1v = bf ? bv1 : av1; unsigned int n1i = bf ? bi1 : ai1;
            float w1v = bf ? av1 : bv1; unsigned int w1i = bf ? ai1 : bi1;
            bool cf = (bv2 < av2) || (bv2 == av2 && bi2 < ai2);
            float c2v = cf ? bv2 : av2; unsigned int c2i = cf ? bi2 : ai2;
            bool df = (c2v < w1v) || (c2v == w1v && c2i < w1i);
            float n2v = df ? c2v : w1v; unsigned int n2i = df ? c2i : w1i;
            rv1[t] = n1v; rv2[t] = n2v; ridx[t] = n1i | (n2i << 16);
        }
    }
    if (lr == 0) {
#pragma unroll
        for (int t = 0; t < 16; ++t) {
            int rl = wr * 64 + (t >> 2) * 16 + kg * 4 + (t & 3);
            size_t o = (size_t)(blockIdx.y * 2 + wc) * N_ROWS + row0 + rl;
            v1o[o] = rv1[t]; v2o[o] = rv2[t]; io[o] = ridx[t];
        }
    }
}

// ---------------------------------------------------------------------------
// Per-row (one wave): merge 4 pool top-2s; if global gap < MARGIN_V, fp64
// re-score all 8 candidates; gather embedding row, loss partial, histogram.
// ---------------------------------------------------------------------------
__global__ __launch_bounds__(64) void vq_gather(const float* __restrict__ x,
                                                const float* __restrict__ emb,
                                                const float* __restrict__ v1,
                                                const float* __restrict__ v2,
                                                const unsigned int* __restrict__ io,
                                                float* __restrict__ out,
                                                int* __restrict__ counts,
                                                float* __restrict__ lossp) {
    const int row = blockIdx.x;
    const int lane = threadIdx.x;

    float V1 = INFINITY, V2 = INFINITY;
    unsigned int I1 = 0xFFFFu, I2 = 0xFFFFu;
#pragma unroll
    for (int p = 0; p < NPOOL; ++p) {
        size_t o = (size_t)p * N_ROWS + row;
        float bv1 = v1[o], bv2 = v2[o];
        unsigned int ox = io[o];
        unsigned int bi1 = ox & 0xFFFFu, bi2 = ox >> 16;
        bool bf = (bv1 < V1) || (bv1 == V1 && bi1 < I1);
        float n1v = bf ? bv1 : V1; unsigned int n1i = bf ? bi1 : I1;
        float w1v = bf ? V1 : bv1; unsigned int w1i = bf ? I1 : bi1;
        bool cf = (bv2 < V2) || (bv2 == V2 && bi2 < I2);
        float c2v = cf ? bv2 : V2; unsigned int c2i = cf ? bi2 : I2;
        bool df = (c2v < w1v) || (c2v == w1v && c2i < w1i);
        V1 = n1v; I1 = n1i;
        V2 = df ? c2v : w1v; I2 = df ? c2i : w1i;
    }

    int c = (int)I1;
    if (V2 - V1 < MARGIN_V) {
        unsigned int cand[8];
#pragma unroll
        for (int p = 0; p < NPOOL; ++p) {
            unsigned int ox = io[(size_t)p * N_ROWS + row];
            cand[2 * p] = ox & 0xFFFFu;
            cand[2 * p + 1] = ox >> 16;
        }
        double xd[8];
#pragma unroll
        for (int kk = 0; kk < 8; ++kk)
            xd[kk] = (double)x[(size_t)row * DIM + lane + 64 * kk];
        double best = 1e300;
        unsigned int bi = 0xFFFFFFFFu;
#pragma unroll
        for (int t = 0; t < 8; ++t) {
            const float* e1 = emb + (size_t)cand[t] * DIM;
            double d = 0.0;
#pragma unroll
            for (int kk = 0; kk < 8; ++kk) {
                double df = xd[kk] - (double)e1[lane + 64 * kk];
                d = fma(df, df, d);
            }
#pragma unroll
            for (int m = 1; m <= 32; m <<= 1) d += __shfl_xor(d, m);
            if (d < best || (d == best && cand[t] < bi)) { best = d; bi = cand[t]; }
        }
        c = (int)bi;
    }

    const float4* xr4 = reinterpret_cast<const float4*>(x + (size_t)row * DIM);
    const float4* er4 = reinterpret_cast<const float4*>(emb + (size_t)c * DIM);
    float4* qo = reinterpret_cast<float4*>(out + (size_t)row * DIM);
    float lsum = 0.f;
#pragma unroll
    for (int k = 0; k < 2; ++k) {
        int idx = lane + 64 * k;
        float4 e = er4[idx];
        float4 xv = xr4[idx];
        qo[idx] = e;
        float dx = xv.x - e.x, dy = xv.y - e.y, dz = xv.z - e.z, dw = xv.w - e.w;
        lsum += dx * dx + dy * dy + dz * dz + dw * dw;
    }
#pragma unroll
    for (int off = 32; off > 0; off >>= 1) lsum += __shfl_down(lsum, off);
    if (lane == 0) {
        lossp[row] = lsum;
        atomicAdd(&counts[c], 1);
        out[Q_OFF + 2 + row] = (float)c;   // indices as float (d_out is f32)
    }
}

// ---------------------------------------------------------------------------
// Single block: fp64 loss sum + perplexity, write scalars.
// ---------------------------------------------------------------------------
__global__ __launch_bounds__(256) void vq_finalize(const float* __restrict__ lossp,
                                                   const int* __restrict__ counts,
                                                   float* __restrict__ out) {
    __shared__ double sred[8];
    const int tid = threadIdx.x;
    const int lane = tid & 63, wv = tid >> 6;
    double ls = 0.0, hs = 0.0;
    for (int r = tid; r < N_ROWS; r += 256) ls += (double)lossp[r];
    for (int cidx = tid; cidx < K_CODES; cidx += 256) {
        double p = (double)counts[cidx] * (1.0 / (double)N_ROWS);
        hs += p * log(p + 1e-10);
    }
#pragma unroll
    for (int off = 32; off > 0; off >>= 1) {
        ls += __shfl_down(ls, off);
        hs += __shfl_down(hs, off);
    }
    if (lane == 0) { sred[wv] = ls; sred[4 + wv] = hs; }
    __syncthreads();
    if (tid == 0) {
        double L = sred[0] + sred[1] + sred[2] + sred[3];
        double H = sred[4] + sred[5] + sred[6] + sred[7];
        out[Q_OFF]     = (float)(0.25 * L / (double)Q_OFF);   // commitment loss
        out[Q_OFF + 1] = (float)exp(-H);                      // perplexity
    }
}

// ---------------------------------------------------------------------------
extern "C" void kernel_launch(void* const* d_in, const int* in_sizes, int n_in,
                              void* d_out, int out_size, void* d_ws, size_t ws_size,
                              hipStream_t stream) {
    const float* x   = (const float*)d_in[0];
    const float* emb = (const float*)d_in[1];
    float* out = (float*)d_out;

    // workspace layout (u32 words)
    unsigned int* w = (unsigned int*)d_ws;
    float* esqh         = (float*)(w);                       // 8192
    int*   counts       = (int*)(w + 8192);                  // 8192
    float* lossp        = (float*)(w + 16384);               // 32768
    float* v1           = (float*)(w + 49152);               // 4*32768
    float* v2           = (float*)(w + 180224);              // 4*32768
    unsigned int* io    = (unsigned int*)(w + 311296);       // 4*32768
    _Float16* x_h       = (_Float16*)(w + 442368);           // 16.7M halves (32 MB)
    _Float16* e_h       = (_Float16*)(w + 8830976);          // 4.2M halves (8 MB)
    const size_t need   = (size_t)10928128 * 4;              // ~43.7 MB

    const bool pk = ws_size >= need;

    vq_esq_init<<<(K_CODES * 64) / 256, 256, 0, stream>>>(emb, esqh, counts);
    if (pk) {
        vq_pack_f16<<<(N_ROWS * DIM / 8) / 256, 256, 0, stream>>>(
            (const float4*)x, (half8*)x_h, N_ROWS * DIM / 8);
        vq_pack_f16<<<(K_CODES * DIM / 8) / 256, 256, 0, stream>>>(
            (const float4*)emb, (half8*)e_h, K_CODES * DIM / 8);
    }

    if (pk) {
        vq_argmin_f16t<<<(N_ROWS / 128) * NSPLIT, 256, 0, stream>>>(
            x_h, e_h, esqh, v1, v2, io);
    } else {
        dim3 grid(N_ROWS / 128, NSPLIT);
        vq_argmin_fb<<<grid, 256, 0, stream>>>(x, emb, esqh, v1, v2, io);
    }

    vq_gather<<<N_ROWS, 64, 0, stream>>>(x, emb, v1, v2, io, out, counts, lossp);
    vq_finalize<<<1, 256, 0, stream>>>(lossp, counts, out);
}

// Round 11
// 485.669 us; speedup vs baseline: 1.3747x; 1.2520x over previous
//
#include <hip/hip_runtime.h>
#include <math.h>

#define N_ROWS 32768
#define K_CODES 8192
#define DIM 512
#define Q_OFF ((size_t)N_ROWS * DIM)   // 16777216 floats of quantized output

#define NSPLIT 4                        // codebook split: 4 pools of 2048 codes (2 MB f16, L2-resident)
#define KSPL (K_CODES / NSPLIT)         // 2048 codes per block
#define NPOOL (NSPLIT * 2)              // 8 disjoint 1024-code pools per row
#define MARGIN_V 0.025f                 // v = d/2 - ||x||^2/2 units; ~23 sigma of f16 err

typedef _Float16 half8 __attribute__((ext_vector_type(8)));
typedef float f32x4 __attribute__((ext_vector_type(4)));

#define GLOAD_LDS(src, dst)                                                        \
  __builtin_amdgcn_global_load_lds(                                                \
      (const __attribute__((address_space(1))) void*)(src),                        \
      (__attribute__((address_space(3))) void*)(dst), 16, 0, 0)

// ---------------------------------------------------------------------------
// f32 -> f16 plane pack (16 floats per thread -> 2 half8)
// ---------------------------------------------------------------------------
__global__ __launch_bounds__(256) void vq_pack_f16(const float4* __restrict__ src,
                                                   half8* __restrict__ dst, int n8) {
    int i = blockIdx.x * 256 + threadIdx.x;
    if (i >= n8) return;
    float4 a = src[i * 2], b = src[i * 2 + 1];
    float v[8] = {a.x, a.y, a.z, a.w, b.x, b.y, b.z, b.w};
    half8 h;
#pragma unroll
    for (int k = 0; k < 8; ++k) h[k] = (_Float16)v[k];
    dst[i] = h;
}

// ---------------------------------------------------------------------------
// zero histogram counts + compute 0.5*||e||^2 per code (one wave/code)
// ---------------------------------------------------------------------------
__global__ __launch_bounds__(256) void vq_esq_init(const float* __restrict__ emb,
                                                   float* __restrict__ esqh,
                                                   int* __restrict__ counts) {
    int gid = blockIdx.x * 256 + threadIdx.x;
    if (gid < K_CODES) counts[gid] = 0;
    int code = gid >> 6;
    int lane = gid & 63;
    const float4* p = reinterpret_cast<const float4*>(emb + (size_t)code * DIM);
    float s = 0.f;
#pragma unroll
    for (int k = 0; k < 2; ++k) {
        float4 v = p[lane + 64 * k];
        s += v.x * v.x + v.y * v.y + v.z * v.z + v.w * v.w;
    }
#pragma unroll
    for (int off = 32; off > 0; off >>= 1) s += __shfl_down(s, off);
    if (lane == 0) esqh[code] = 0.5f * s;
}

// ---------------------------------------------------------------------------
// Fragment read, quad-buffer kernel: tile row-major [128 rows][32 halves],
// 16B slots XOR-swizzled by ((row>>2)&3).
// ---------------------------------------------------------------------------
__device__ __forceinline__ half8 fragq(const _Float16* t, int row, int kg) {
    return *reinterpret_cast<const half8*>(t + row * 32 + ((kg ^ ((row >> 2) & 3)) << 3));
}

// old-swizzle reader, used by fallback kernel only
__device__ __forceinline__ half8 frag16(const _Float16* t, int row, int kg) {
    return *reinterpret_cast<const half8*>(t + row * 32 + ((kg ^ (row & 3)) << 3));
}

// ---------------------------------------------------------------------------
// MFMA argmin, single f16 plane, quad-buffered pipeline (r6-proven, best
// measured: 377 us @ NSPLIT=2).  Block tile 128 rows x 128 codes, 4 waves
// (wr 2 x wc 2), wave 64x64 via 4x4 frags of mfma_f32_16x16x32_f16.
// 4 LDS buffers x 16 KB (A 4096 | B 4096 halves) = 64 KB, 2 blocks/CU.
// Depth-2 global_load_lds prefetch, counted s_waitcnt vmcnt(4) + raw
// s_barrier per K-step; buffer index = ks&3 COMPILE-TIME (inner loop fully
// unrolled, 16 steps/cc-tile).  Last cc-tile peeled (drain).
// ONLY change vs r6: NSPLIT=4 -> each block sweeps a 2 MB codebook quarter
// that stays L2-resident (kills the ~40% HBM-miss B-reads seen at NSPLIT=2).
// v = 0.5||e||^2 - x.e ; per-lane running top-2 -> shfl_xor tree at end.
// ---------------------------------------------------------------------------
__global__ __launch_bounds__(256, 2) void vq_argmin_f16q(
        const _Float16* __restrict__ xh, const _Float16* __restrict__ eh,
        const float* __restrict__ esqh,
        float* __restrict__ v1o, float* __restrict__ v2o,
        unsigned int* __restrict__ io) {
    __shared__ __align__(16) _Float16 sbuf[4][8192];   // per buf: A 4096 | B 4096 halves

    const int tid = threadIdx.x;
    const int lane = tid & 63;
    const int wid = tid >> 6;
    const int wr = wid >> 1, wc = wid & 1;
    const int lr = lane & 15, kg = lane >> 4;
    const int row0 = blockIdx.x * 128;
    const int csplit0 = blockIdx.y * KSPL;

    // staging: per-lane inverse-swizzled global offset, wave-uniform LDS dest.
    int off[2], dstA[2], dstB[2];
#pragma unroll
    for (int c = 0; c < 2; ++c) {
        int r = wid * 32 + c * 16 + (lane >> 2);
        int sx = (lane & 3) ^ ((r >> 2) & 3);
        off[c] = r * DIM + sx * 8;
        dstA[c] = (wid * 32 + c * 16) * 32;
        dstB[c] = 4096 + dstA[c];
    }

    auto stage = [&](int b, int s) {   // s = flat K-step (cc*16 + ks)
        int cc = s >> 4, ks = s & 15;
        const _Float16* a0 = xh + (size_t)row0 * DIM + ks * 32;
        const _Float16* b0 = eh + (size_t)(csplit0 + cc * 128) * DIM + ks * 32;
        _Float16* base = &sbuf[b][0];
#pragma unroll
        for (int c = 0; c < 2; ++c) {
            GLOAD_LDS(a0 + off[c], base + dstA[c]);
            GLOAD_LDS(b0 + off[c], base + dstB[c]);
        }
    };

    auto compute = [&](int bq, f32x4 (&acc)[4][4]) {
        const _Float16* A = &sbuf[bq][0];
        const _Float16* B = &sbuf[bq][4096];
        half8 a[4], b[4];
#pragma unroll
        for (int i = 0; i < 4; ++i) a[i] = fragq(A, wr * 64 + i * 16 + lr, kg);
#pragma unroll
        for (int j = 0; j < 4; ++j) b[j] = fragq(B, wc * 64 + j * 16 + lr, kg);
#pragma unroll
        for (int j = 0; j < 4; ++j)
#pragma unroll
            for (int i = 0; i < 4; ++i)
                acc[i][j] = __builtin_amdgcn_mfma_f32_16x16x32_f16(a[i], b[j], acc[i][j], 0, 0, 0);
    };

    float rv1[16], rv2[16];
    unsigned int ridx[16];
#pragma unroll
    for (int t = 0; t < 16; ++t) { rv1[t] = INFINITY; rv2[t] = INFINITY; ridx[t] = 0; }

    auto fold = [&](int cc, f32x4 (&acc)[4][4]) {
#pragma unroll
        for (int j = 0; j < 4; ++j) {
            int cg = csplit0 + cc * 128 + wc * 64 + j * 16 + lr;
            float eqv = esqh[cg];
#pragma unroll
            for (int i = 0; i < 4; ++i) {
#pragma unroll
                for (int r = 0; r < 4; ++r) {
                    float v = eqv - acc[i][j][r];
                    int t = i * 4 + r;
                    if (v < rv1[t]) {
                        rv2[t] = rv1[t]; ridx[t] = (ridx[t] << 16) | (unsigned int)cg; rv1[t] = v;
                    } else if (v < rv2[t]) {
                        rv2[t] = v; ridx[t] = (ridx[t] & 0xFFFFu) | ((unsigned int)cg << 16);
                    }
                }
            }
        }
    };

    const int NCC = KSPL / 128;   // 16 cc-tiles, 16 K-steps each
    stage(0, 0);
    stage(1, 1);

    for (int cc = 0; cc < NCC - 1; ++cc) {
        f32x4 acc[4][4];
#pragma unroll
        for (int i = 0; i < 4; ++i)
#pragma unroll
            for (int j = 0; j < 4; ++j) acc[i][j] = (f32x4)(0.f);
#pragma unroll
        for (int ks = 0; ks < 16; ++ks) {
            asm volatile("s_waitcnt vmcnt(4)" ::: "memory");
            __builtin_amdgcn_s_barrier();
            stage((ks + 2) & 3, cc * 16 + ks + 2);
            compute(ks & 3, acc);
        }
        fold(cc, acc);
    }
    {   // peeled last cc-tile: finish staging (ks<14), drain at ks==15
        const int cc = NCC - 1;
        f32x4 acc[4][4];
#pragma unroll
        for (int i = 0; i < 4; ++i)
#pragma unroll
            for (int j = 0; j < 4; ++j) acc[i][j] = (f32x4)(0.f);
#pragma unroll
        for (int ks = 0; ks < 16; ++ks) {
            if (ks == 15) asm volatile("s_waitcnt vmcnt(0)" ::: "memory");
            else          asm volatile("s_waitcnt vmcnt(4)" ::: "memory");
            __builtin_amdgcn_s_barrier();
            if (ks < 14) stage((ks + 2) & 3, cc * 16 + ks + 2);
            compute(ks & 3, acc);
        }
        fold(cc, acc);
    }

    // cross-lane top-2 merge within each 16-lane group (same rows, disjoint cols)
#pragma unroll
    for (int m = 1; m <= 8; m <<= 1) {
#pragma unroll
        for (int t = 0; t < 16; ++t) {
            float bv1 = __shfl_xor(rv1[t], m);
            float bv2 = __shfl_xor(rv2[t], m);
            unsigned int ox = (unsigned int)__shfl_xor((int)ridx[t], m);
            unsigned int ai1 = ridx[t] & 0xFFFFu, ai2 = ridx[t] >> 16;
            unsigned int bi1 = ox & 0xFFFFu, bi2 = ox >> 16;
            float av1 = rv1[t], av2 = rv2[t];
            bool bf = (bv1 < av1) || (bv1 == av1 && bi1 < ai1);
            float n1v = bf ? bv1 : av1; unsigned int n1i = bf ? bi1 : ai1;
            float w1v = bf ? av1 : bv1; unsigned int w1i = bf ? ai1 : bi1;
            bool cf = (bv2 < av2) || (bv2 == av2 && bi2 < ai2);
            float c2v = cf ? bv2 : av2; unsigned int c2i = cf ? bi2 : ai2;
            bool df = (c2v < w1v) || (c2v == w1v && c2i < w1i);
            float n2v = df ? c2v : w1v; unsigned int n2i = df ? c2i : w1i;
            rv1[t] = n1v; rv2[t] = n2v; ridx[t] = n1i | (n2i << 16);
        }
    }

    if (lr == 0) {
#pragma unroll
        for (int t = 0; t < 16; ++t) {
            int rl = wr * 64 + (t >> 2) * 16 + kg * 4 + (t & 3);
            size_t o = (size_t)(blockIdx.y * 2 + wc) * N_ROWS + row0 + rl;
            v1o[o] = rv1[t]; v2o[o] = rv2[t]; io[o] = ridx[t];
        }
    }
}

// ---------------------------------------------------------------------------
// Fallback (workspace too small): reg-staged f32->f16, double-buffer,
// __syncthreads, 128x256 tile, 4 waves.  Correctness path only.
// ---------------------------------------------------------------------------
__global__ __launch_bounds__(256, 2) void vq_argmin_fb(
        const float* __restrict__ xf, const float* __restrict__ ef,
        const float* __restrict__ esqh,
        float* __restrict__ v1o, float* __restrict__ v2o,
        unsigned int* __restrict__ io) {
    __shared__ __align__(16) _Float16 sbuf[2][12288];

    const int tid = threadIdx.x;
    const int lane = tid & 63;
    const int wid = tid >> 6;
    const int wr = wid >> 1, wc = wid & 1;
    const int lr = lane & 15, kg = lane >> 4;
    const int row0 = blockIdx.x * 128;
    const int csplit0 = blockIdx.y * KSPL;

    auto stage = [&](int b, int s) {
        int cc = s >> 4, ks = s & 15;
        {
            const int r = tid >> 1;
            const int k0 = (tid & 1) * 16;
            const float4* xp = reinterpret_cast<const float4*>(
                xf + (size_t)(row0 + r) * DIM + ks * 32 + k0);
            float4 f0 = xp[0], f1 = xp[1], f2 = xp[2], f3 = xp[3];
            float v[16] = {f0.x, f0.y, f0.z, f0.w, f1.x, f1.y, f1.z, f1.w,
                           f2.x, f2.y, f2.z, f2.w, f3.x, f3.y, f3.z, f3.w};
            half8 h0, h1;
#pragma unroll
            for (int k = 0; k < 8; ++k) { h0[k] = (_Float16)v[k]; h1[k] = (_Float16)v[8 + k]; }
            int s0 = (k0 >> 3) ^ (r & 3);
            int s1 = ((k0 >> 3) + 1) ^ (r & 3);
            _Float16* Ah = &sbuf[b][0];
            *reinterpret_cast<half8*>(Ah + r * 32 + s0 * 8) = h0;
            *reinterpret_cast<half8*>(Ah + r * 32 + s1 * 8) = h1;
        }
        {
            const int r = tid;
            const float4* ep = reinterpret_cast<const float4*>(
                ef + (size_t)(csplit0 + cc * 256 + r) * DIM + ks * 32);
            _Float16* Be = &sbuf[b][4096];
#pragma unroll
            for (int q = 0; q < 4; ++q) {
                float4 g0 = ep[q * 2], g1 = ep[q * 2 + 1];
                half8 h;
                h[0] = (_Float16)g0.x; h[1] = (_Float16)g0.y;
                h[2] = (_Float16)g0.z; h[3] = (_Float16)g0.w;
                h[4] = (_Float16)g1.x; h[5] = (_Float16)g1.y;
                h[6] = (_Float16)g1.z; h[7] = (_Float16)g1.w;
                *reinterpret_cast<half8*>(Be + r * 32 + ((q ^ (r & 3)) << 3)) = h;
            }
        }
    };

    float rv1[16], rv2[16];
    unsigned int ridx[16];
#pragma unroll
    for (int t = 0; t < 16; ++t) { rv1[t] = INFINITY; rv2[t] = INFINITY; ridx[t] = 0; }

    f32x4 acc[4][8];
    const int NS = (KSPL / 256) * 16;
    int cur = 0;
    stage(0, 0);
    __syncthreads();
    for (int s = 0; s < NS; ++s) {
        if ((s & 15) == 0) {
#pragma unroll
            for (int i = 0; i < 4; ++i)
#pragma unroll
                for (int j = 0; j < 8; ++j) acc[i][j] = (f32x4)(0.f);
        }
        const _Float16* Ah = &sbuf[cur][0];
        const _Float16* Be = &sbuf[cur][4096];
        half8 a[4];
#pragma unroll
        for (int i = 0; i < 4; ++i) a[i] = frag16(Ah, wr * 64 + i * 16 + lr, kg);
#pragma unroll
        for (int j = 0; j < 8; ++j) {
            half8 b = frag16(Be, wc * 128 + j * 16 + lr, kg);
#pragma unroll
            for (int i = 0; i < 4; ++i)
                acc[i][j] = __builtin_amdgcn_mfma_f32_16x16x32_f16(a[i], b, acc[i][j], 0, 0, 0);
        }
        if (s + 1 < NS) stage(cur ^ 1, s + 1);
        if ((s & 15) == 15) {
            int cc = s >> 4;
#pragma unroll
            for (int j = 0; j < 8; ++j) {
                int cg = csplit0 + cc * 256 + wc * 128 + j * 16 + lr;
                float eqv = esqh[cg];
#pragma unroll
                for (int i = 0; i < 4; ++i) {
#pragma unroll
                    for (int r = 0; r < 4; ++r) {
                        float v = eqv - acc[i][j][r];
                        int t = i * 4 + r;
                        if (v < rv1[t]) {
                            rv2[t] = rv1[t]; ridx[t] = (ridx[t] << 16) | (unsigned int)cg; rv1[t] = v;
                        } else if (v < rv2[t]) {
                            rv2[t] = v; ridx[t] = (ridx[t] & 0xFFFFu) | ((unsigned int)cg << 16);
                        }
                    }
                }
            }
        }
        __syncthreads();
        cur ^= 1;
    }

#pragma unroll
    for (int m = 1; m <= 8; m <<= 1) {
#pragma unroll
        for (int t = 0; t < 16; ++t) {
            float bv1 = __shfl_xor(rv1[t], m);
            float bv2 = __shfl_xor(rv2[t], m);
            unsigned int ox = (unsigned int)__shfl_xor((int)ridx[t], m);
            unsigned int ai1 = ridx[t] & 0xFFFFu, ai2 = ridx[t] >> 16;
            unsigned int bi1 = ox & 0xFFFFu, bi2 = ox >> 16;
            float av1 = rv1[t], av2 = rv2[t];
            bool bf = (bv1 < av1) || (bv1 == av1 && bi1 < ai1);
            float n1v = bf ? bv1 : av1; unsigned int n1i = bf ? bi1 : ai1;
            float w1v = bf ? av1 : bv1; unsigned int w1i = bf ? ai1 : bi1;
            bool cf = (bv2 < av2) || (bv2 == av2 && bi2 < ai2);
            float c2v = cf ? bv2 : av2; unsigned int c2i = cf ? bi2 : ai2;
            bool df = (c2v < w1v) || (c2v == w1v && c2i < w1i);
            float n2v = df ? c2v : w1v; unsigned int n2i = df ? c2i : w1i;
            rv1[t] = n1v; rv2[t] = n2v; ridx[t] = n1i | (n2i << 16);
        }
    }
    if (lr == 0) {
#pragma unroll
        for (int t = 0; t < 16; ++t) {
            int rl = wr * 64 + (t >> 2) * 16 + kg * 4 + (t & 3);
            size_t o = (size_t)(blockIdx.y * 2 + wc) * N_ROWS + row0 + rl;
            v1o[o] = rv1[t]; v2o[o] = rv2[t]; io[o] = ridx[t];
        }
    }
}

// ---------------------------------------------------------------------------
// Per-row (one wave): merge 8 pool top-2s; if global gap < MARGIN_V, fp64
// re-score all 16 candidates; gather embedding row, loss partial, histogram.
// ---------------------------------------------------------------------------
__global__ __launch_bounds__(64) void vq_gather(const float* __restrict__ x,
                                                const float* __restrict__ emb,
                                                const float* __restrict__ v1,
                                                const float* __restrict__ v2,
                                                const unsigned int* __restrict__ io,
                                                float* __restrict__ out,
                                                int* __restrict__ counts,
                                                float* __restrict__ lossp) {
    const int row = blockIdx.x;
    const int lane = threadIdx.x;

    float V1 = INFINITY, V2 = INFINITY;
    unsigned int I1 = 0xFFFFu, I2 = 0xFFFFu;
#pragma unroll
    for (int p = 0; p < NPOOL; ++p) {
        size_t o = (size_t)p * N_ROWS + row;
        float bv1 = v1[o], bv2 = v2[o];
        unsigned int ox = io[o];
        unsigned int bi1 = ox & 0xFFFFu, bi2 = ox >> 16;
        bool bf = (bv1 < V1) || (bv1 == V1 && bi1 < I1);
        float n1v = bf ? bv1 : V1; unsigned int n1i = bf ? bi1 : I1;
        float w1v = bf ? V1 : bv1; unsigned int w1i = bf ? I1 : bi1;
        bool cf = (bv2 < V2) || (bv2 == V2 && bi2 < I2);
        float c2v = cf ? bv2 : V2; unsigned int c2i = cf ? bi2 : I2;
        bool df = (c2v < w1v) || (c2v == w1v && c2i < w1i);
        V1 = n1v; I1 = n1i;
        V2 = df ? c2v : w1v; I2 = df ? c2i : w1i;
    }

    int c = (int)I1;
    if (V2 - V1 < MARGIN_V) {
        unsigned int cand[2 * NPOOL];
#pragma unroll
        for (int p = 0; p < NPOOL; ++p) {
            unsigned int ox = io[(size_t)p * N_ROWS + row];
            cand[2 * p] = ox & 0xFFFFu;
            cand[2 * p + 1] = ox >> 16;
        }
        double xd[8];
#pragma unroll
        for (int kk = 0; kk < 8; ++kk)
            xd[kk] = (double)x[(size_t)row * DIM + lane + 64 * kk];
        double best = 1e300;
        unsigned int bi = 0xFFFFFFFFu;
#pragma unroll
        for (int t = 0; t < 2 * NPOOL; ++t) {
            const float* e1 = emb + (size_t)cand[t] * DIM;
            double d = 0.0;
#pragma unroll
            for (int kk = 0; kk < 8; ++kk) {
                double df = xd[kk] - (double)e1[lane + 64 * kk];
                d = fma(df, df, d);
            }
#pragma unroll
            for (int m = 1; m <= 32; m <<= 1) d += __shfl_xor(d, m);
            if (d < best || (d == best && cand[t] < bi)) { best = d; bi = cand[t]; }
        }
        c = (int)bi;
    }

    const float4* xr4 = reinterpret_cast<const float4*>(x + (size_t)row * DIM);
    const float4* er4 = reinterpret_cast<const float4*>(emb + (size_t)c * DIM);
    float4* qo = reinterpret_cast<float4*>(out + (size_t)row * DIM);
    float lsum = 0.f;
#pragma unroll
    for (int k = 0; k < 2; ++k) {
        int idx = lane + 64 * k;
        float4 e = er4[idx];
        float4 xv = xr4[idx];
        qo[idx] = e;
        float dx = xv.x - e.x, dy = xv.y - e.y, dz = xv.z - e.z, dw = xv.w - e.w;
        lsum += dx * dx + dy * dy + dz * dz + dw * dw;
    }
#pragma unroll
    for (int off = 32; off > 0; off >>= 1) lsum += __shfl_down(lsum, off);
    if (lane == 0) {
        lossp[row] = lsum;
        atomicAdd(&counts[c], 1);
        out[Q_OFF + 2 + row] = (float)c;   // indices as float (d_out is f32)
    }
}

// ---------------------------------------------------------------------------
// Single block: fp64 loss sum + perplexity, write scalars.
// ---------------------------------------------------------------------------
__global__ __launch_bounds__(256) void vq_finalize(const float* __restrict__ lossp,
                                                   const int* __restrict__ counts,
                                                   float* __restrict__ out) {
    __shared__ double sred[8];
    const int tid = threadIdx.x;
    const int lane = tid & 63, wv = tid >> 6;
    double ls = 0.0, hs = 0.0;
    for (int r = tid; r < N_ROWS; r += 256) ls += (double)lossp[r];
    for (int cidx = tid; cidx < K_CODES; cidx += 256) {
        double p = (double)counts[cidx] * (1.0 / (double)N_ROWS);
        hs += p * log(p + 1e-10);
    }
#pragma unroll
    for (int off = 32; off > 0; off >>= 1) {
        ls += __shfl_down(ls, off);
        hs += __shfl_down(hs, off);
    }
    if (lane == 0) { sred[wv] = ls; sred[4 + wv] = hs; }
    __syncthreads();
    if (tid == 0) {
        double L = sred[0] + sred[1] + sred[2] + sred[3];
        double H = sred[4] + sred[5] + sred[6] + sred[7];
        out[Q_OFF]     = (float)(0.25 * L / (double)Q_OFF);   // commitment loss
        out[Q_OFF + 1] = (float)exp(-H);                      // perplexity
    }
}

// ---------------------------------------------------------------------------
extern "C" void kernel_launch(void* const* d_in, const int* in_sizes, int n_in,
                              void* d_out, int out_size, void* d_ws, size_t ws_size,
                              hipStream_t stream) {
    const float* x   = (const float*)d_in[0];
    const float* emb = (const float*)d_in[1];
    float* out = (float*)d_out;

    // workspace layout (u32 words)
    unsigned int* w = (unsigned int*)d_ws;
    float* esqh         = (float*)(w);                       // 8192
    int*   counts       = (int*)(w + 8192);                  // 8192
    float* lossp        = (float*)(w + 16384);               // 32768
    float* v1           = (float*)(w + 49152);               // 8*32768
    float* v2           = (float*)(w + 311296);              // 8*32768
    unsigned int* io    = (unsigned int*)(w + 573440);       // 8*32768
    _Float16* x_h       = (_Float16*)(w + 835584);           // 16.7M halves (32 MB)
    _Float16* e_h       = (_Float16*)(w + 9224192);          // 4.2M halves (8 MB)
    const size_t need   = (size_t)11321344 * 4;              // ~45.3 MB

    const bool pk = ws_size >= need;

    vq_esq_init<<<(K_CODES * 64) / 256, 256, 0, stream>>>(emb, esqh, counts);
    if (pk) {
        vq_pack_f16<<<(N_ROWS * DIM / 8) / 256, 256, 0, stream>>>(
            (const float4*)x, (half8*)x_h, N_ROWS * DIM / 8);
        vq_pack_f16<<<(K_CODES * DIM / 8) / 256, 256, 0, stream>>>(
            (const float4*)emb, (half8*)e_h, K_CODES * DIM / 8);
    }

    dim3 grid(N_ROWS / 128, NSPLIT);
    if (pk)
        vq_argmin_f16q<<<grid, 256, 0, stream>>>(x_h, e_h, esqh, v1, v2, io);
    else
        vq_argmin_fb<<<grid, 256, 0, stream>>>(x, emb, esqh, v1, v2, io);

    vq_gather<<<N_ROWS, 64, 0, stream>>>(x, emb, v1, v2, io, out, counts, lossp);
    vq_finalize<<<1, 256, 0, stream>>>(lossp, counts, out);
}